// Round 1
// baseline (136.850 us; speedup 1.0000x reference)
//
#include <hip/hip_runtime.h>

// Problem: x[B=32, C=512, H=256, W=14] f32; per-(b,h) shuffle of the 7
// same-parity columns (parity = h%2): out[b,c,h,2j+p] = x[b,c,h,2*perm[b,h,j]+p],
// opposite-parity columns identity. Pure gather along W, broadcast over C.
//
// Flat index: idx = ((b*C + c)*H + h)*W + w, row = idx/14, h = row & 255,
// b = row >> 17 (C*H = 131072 = 2^17). N = 58,720,256 (divisible by 4).

__global__ __launch_bounds__(256) void GSRS_shuffle_kernel(
    const float* __restrict__ x,
    const int* __restrict__ perms,
    float* __restrict__ out,
    unsigned n4)
{
    const unsigned stride = gridDim.x * blockDim.x;
    for (unsigned t = blockIdx.x * blockDim.x + threadIdx.x; t < n4; t += stride) {
        const unsigned g = t * 4u;
        unsigned row = g / 14u;           // magic-mul, compile-time const divisor
        unsigned w   = g - row * 14u;
        float v[4];
#pragma unroll
        for (int k = 0; k < 4; ++k) {
            const unsigned h = row & 255u;
            const unsigned b = row >> 17;
            const unsigned p = h & 1u;
            unsigned src;
            if ((w & 1u) == p) {
                // shuffled slot: j = w>>1 (valid since w = 2j + p)
                src = 2u * (unsigned)perms[(b * 256u + h) * 7u + (w >> 1)] + p;
            } else {
                src = w;                  // identity slot
            }
            v[k] = x[row * 14u + src];
            ++w;
            if (w == 14u) { w = 0u; ++row; }
        }
        *reinterpret_cast<float4*>(out + g) = make_float4(v[0], v[1], v[2], v[3]);
    }
}

extern "C" void kernel_launch(void* const* d_in, const int* in_sizes, int n_in,
                              void* d_out, int out_size, void* d_ws, size_t ws_size,
                              hipStream_t stream) {
    const float* x     = (const float*)d_in[0];
    const int*   perms = (const int*)d_in[1];
    float*       out   = (float*)d_out;

    const unsigned n4 = (32u * 512u * 256u * 14u) / 4u;  // 14,680,064 float4 groups
    // 2048 blocks x 256 threads = 8 wg/CU on 256 CUs -> full wave occupancy,
    // each thread runs 28 grid-stride iterations.
    const int blocks = 2048;
    hipLaunchKernelGGL(GSRS_shuffle_kernel, dim3(blocks), dim3(256), 0, stream,
                       x, perms, out, n4);
}

// Round 2
// 89.159 us; speedup vs baseline: 1.5349x; 1.5349x over previous
//
#include <hip/hip_runtime.h>

// x[B=32, C=512, H=256, W=14] f32. Per-(b,h) shuffle of the 7 same-parity
// columns (p = h%2): out[b,c,h,2j+p] = x[b,c,h,2*perm[b,h,j]+p]; other
// columns identity. Pure within-row (56 B) gather, broadcast over C.
//
// Strategy: both global streams float4-coalesced; the shuffle happens in LDS.
//   row = flat/14; h = row & 255; b = row >> 17 (C*H = 2^17).
//   TILE = 512 consecutive rows = 7168 floats = 1792 float4 per block.
//   b is constant per tile (512 | 131072), h cycles 0..255 twice.

#define TILE_ROWS   512
#define TILE_FLOATS (TILE_ROWS * 14)        // 7168
#define TILE_VEC4   (TILE_FLOATS / 4)       // 1792 = 7 * 256

__global__ __launch_bounds__(256) void GSRS_shuffle_lds_kernel(
    const float* __restrict__ x,
    const int* __restrict__ perms,
    float* __restrict__ out)
{
    __shared__ float tile[TILE_FLOATS];     // 28 KB
    __shared__ int   lperm[256 * 7];        // 7 KB, layout [h][j]

    const unsigned tid  = threadIdx.x;
    const unsigned tb   = blockIdx.x;       // tile index, 0..8191
    const unsigned base = tb * TILE_FLOATS; // float offset of tile
    const unsigned row0 = tb * TILE_ROWS;
    const unsigned b    = row0 >> 17;       // batch, constant per tile

    // Stage perms slice for this b: 1792 ints, linear copy (coalesced).
    const int* pslice = perms + b * (256 * 7);
#pragma unroll
    for (int i = 0; i < 7; ++i)
        lperm[i * 256 + tid] = pslice[i * 256 + tid];

    // Stage x tile: 1792 float4, linear copy (coalesced dwordx4).
    const float4* xv = reinterpret_cast<const float4*>(x + base);
    float4*       tv = reinterpret_cast<float4*>(tile);
#pragma unroll
    for (int i = 0; i < 7; ++i)
        tv[i * 256 + tid] = xv[i * 256 + tid];

    __syncthreads();

    // Gather from LDS, store coalesced float4.
    float4* ov = reinterpret_cast<float4*>(out + base);
#pragma unroll
    for (int i = 0; i < 7; ++i) {
        const unsigned q  = i * 256 + tid;  // float4 index within tile
        unsigned lo   = q * 4u;             // float offset within tile
        unsigned lrow = lo / 14u;           // local row (== h pattern: lrow & 255)
        unsigned w    = lo - lrow * 14u;
        float v[4];
#pragma unroll
        for (int k = 0; k < 4; ++k) {
            const unsigned h = lrow & 255u; // (row0 + lrow) & 255 == lrow & 255
            const unsigned p = h & 1u;
            unsigned src;
            if ((w & 1u) == p)
                src = 2u * (unsigned)lperm[h * 7u + (w >> 1)] + p;
            else
                src = w;
            v[k] = tile[lrow * 14u + src];
            if (++w == 14u) { w = 0u; ++lrow; }
        }
        ov[q] = make_float4(v[0], v[1], v[2], v[3]);
    }
}

extern "C" void kernel_launch(void* const* d_in, const int* in_sizes, int n_in,
                              void* d_out, int out_size, void* d_ws, size_t ws_size,
                              hipStream_t stream) {
    const float* x     = (const float*)d_in[0];
    const int*   perms = (const int*)d_in[1];
    float*       out   = (float*)d_out;

    // 4,194,304 rows / 512 rows per tile = 8192 tiles, one block each.
    hipLaunchKernelGGL(GSRS_shuffle_lds_kernel, dim3(8192), dim3(256), 0, stream,
                       x, perms, out);
}